// Round 18
// baseline (176.996 us; speedup 1.0000x reference)
//
#include <hip/hip_runtime.h>

#define NVAR 2048
#define DM   512
#define J3   1536

typedef _Float16 f16;
typedef _Float16 f16x8 __attribute__((ext_vector_type(8)));
typedef _Float16 f16x4 __attribute__((ext_vector_type(4)));
typedef float    f32x4 __attribute__((ext_vector_type(4)));

#define SBAR() do { asm volatile("s_barrier" ::: "memory"); \
                    __builtin_amdgcn_sched_barrier(0); } while(0)
#define LGKM0() do { asm volatile("s_waitcnt lgkmcnt(0)" ::: "memory"); \
                     __builtin_amdgcn_sched_barrier(0); } while(0)
#define GLOAD(gp, lp) __builtin_amdgcn_global_load_lds( \
    (const __attribute__((address_space(1))) void*)(gp), \
    (__attribute__((address_space(3))) void*)(lp), 16, 0, 0)

__device__ __forceinline__ void waitvm_n(int n) {
    switch (n) {
    case 0: asm volatile("s_waitcnt vmcnt(0)" ::: "memory"); break;
    case 1: asm volatile("s_waitcnt vmcnt(1)" ::: "memory"); break;
    case 2: asm volatile("s_waitcnt vmcnt(2)" ::: "memory"); break;
    case 3: asm volatile("s_waitcnt vmcnt(3)" ::: "memory"); break;
    case 4: asm volatile("s_waitcnt vmcnt(4)" ::: "memory"); break;
    case 5: asm volatile("s_waitcnt vmcnt(5)" ::: "memory"); break;
    case 6: asm volatile("s_waitcnt vmcnt(6)" ::: "memory"); break;
    case 7: asm volatile("s_waitcnt vmcnt(7)" ::: "memory"); break;
    case 8: asm volatile("s_waitcnt vmcnt(8)" ::: "memory"); break;
    default: break;
    }
    __builtin_amdgcn_sched_barrier(0);
}

// ---------------------------------------------------------------------------
// Transpose fp32 [R][C] -> f16 [C][R] (per grid.z batch), vectorized
// ---------------------------------------------------------------------------
__global__ __launch_bounds__(256)
void k_tr(const float* __restrict__ src, f16* __restrict__ dst,
          int R, int C, long bsSrc, long bsDst) {
    __shared__ float t[64][65];
    const float* s = src + (size_t)blockIdx.z * bsSrc;
    f16* d = dst + (size_t)blockIdx.z * bsDst;
    const int c0 = blockIdx.x * 64, r0 = blockIdx.y * 64;
    const int lx = threadIdx.x & 15, ly = threadIdx.x >> 4;
#pragma unroll
    for (int p = 0; p < 4; ++p) {
        int r = p * 16 + ly;
        f32x4 v = *(const f32x4*)(s + (size_t)(r0 + r) * C + c0 + lx * 4);
#pragma unroll
        for (int i = 0; i < 4; ++i) t[r][lx * 4 + i] = v[i];
    }
    __syncthreads();
#pragma unroll
    for (int p = 0; p < 4; ++p) {
        int c = p * 16 + ly;
        f16x4 h;
#pragma unroll
        for (int i = 0; i < 4; ++i) h[i] = (f16)t[lx * 4 + i][c];
        *(f16x4*)(d + (size_t)(c0 + c) * R + r0 + lx * 4) = h;
    }
}

// ---------------------------------------------------------------------------
// Cast Wqkv[:,1024:1536] fp32 -> f16 Wq2[d][j]
// ---------------------------------------------------------------------------
__global__ __launch_bounds__(256)
void k_cast(const float* __restrict__ W, f16* __restrict__ out) {
    int idx = blockIdx.x * 256 + threadIdx.x;
    int gi = idx * 4;
    int d = gi >> 9, j = gi & 511;
    f32x4 v = *(const f32x4*)(W + (size_t)d * J3 + 1024 + j);
    f16x4 h;
#pragma unroll
    for (int i = 0; i < 4; ++i) h[i] = (f16)v[i];
    *(f16x4*)(out + (size_t)d * 512 + j) = h;
}

// ---------------------------------------------------------------------------
// bias_c: [0:1024] = bqkv[0:1024]; [1024+l] = sum_j bqkv[1024+j]*Wp[j][l].
// ---------------------------------------------------------------------------
__global__ __launch_bounds__(256)
void k_bvp(const float* __restrict__ bqkv, const float* __restrict__ Wp,
           float* __restrict__ bias_c) {
    const int b = blockIdx.x;
    const int lt = threadIdx.x & 63, js = threadIdx.x >> 6;
    const int l = b * 64 + lt;
    float s = 0.f;
    for (int j = js * 128; j < js * 128 + 128; ++j)
        s += bqkv[1024 + j] * Wp[(size_t)j * DM + l];
    __shared__ float red[4][64];
    red[js][lt] = s;
    __syncthreads();
    if (js == 0)
        bias_c[1024 + l] = (red[0][lt] + red[1][lt]) + (red[2][lt] + red[3][lt]);
    if (threadIdx.x < 128) {
        int i = b * 128 + threadIdx.x;
        bias_c[i] = bqkv[i];
    }
}

// ---------------------------------------------------------------------------
// S' 8-phase counted-vmcnt GEMM (r10/r12/r17-proven, unchanged): 256x256,
// BK=64, 512 thr, 8 waves (2Mx4N), wave 128x64.  A x3 + B x2 LDS = 160 KiB.
// Epilogue: exp(acc*scale) -> LDS bounce -> 512B-coalesced stores.
// ---------------------------------------------------------------------------
#define ASZ (256 * 64)
__global__ __launch_bounds__(512, 2)
void gemm_sp(const f16* __restrict__ A, const f16* __restrict__ B,
             long bsA, long bsB, int lda, int ldb, int K,
             float scale, f16* __restrict__ o0) {
    __shared__ f16 smem[5 * ASZ];
    f16* sA = smem;
    f16* sB = smem + 3 * ASZ;

    const int tid  = threadIdx.x;
    const int lane = tid & 63;
    const int w    = __builtin_amdgcn_readfirstlane(tid >> 6);
    const int wm   = (w >> 2) * 128;       // A-dim (m)
    const int wn   = (w & 3) * 64;         // B-dim (n)
    const int z    = blockIdx.x;
    const int bid  = blockIdx.y;
    const int bxA  = bid & 7;
    const int bxB  = bid >> 3;

    const f16* Ab = A + (size_t)z * bsA + (size_t)bxA * 256 * lda;
    const f16* Bb = B + (size_t)z * bsB + (size_t)bxB * 256 * ldb;

    int offA[2][2], offB[2][2];
#pragma unroll
    for (int h = 0; h < 2; ++h)
#pragma unroll
        for (int i = 0; i < 2; ++i) {
            int slot = i * 512 + tid;
            int row  = h * 128 + (slot >> 3);
            int s    = (slot & 7) ^ (row & 7);
            offA[h][i] = row * lda + s * 8;
            offB[h][i] = row * ldb + s * 8;
        }

    auto STG_A = [&](int kt, int h, int buf) {
        f16* d = sA + buf * ASZ + h * 8192;
#pragma unroll
        for (int i = 0; i < 2; ++i)
            GLOAD(Ab + offA[h][i] + kt * 64, d + (i * 512 + tid) * 8);
    };
    auto STG_B = [&](int kt, int h, int buf) {
        f16* d = sB + buf * ASZ + h * 8192;
#pragma unroll
        for (int i = 0; i < 2; ++i)
            GLOAD(Bb + offB[h][i] + kt * 64, d + (i * 512 + tid) * 8);
    };

    int koff[2];
#pragma unroll
    for (int ks = 0; ks < 2; ++ks)
        koff[ks] = ((ks * 4 + (lane >> 4)) ^ (lane & 7)) * 8;
    const int rowA = (wm + (lane & 15)) * 64;
    const int rowB = (wn + (lane & 15)) * 64;

    f16x8 av[8][2], bv[4][2];
    f32x4 acc[8][4] = {};

    auto LD_AV = [&](const f16* p, int mi0) {
#pragma unroll
        for (int mi = 0; mi < 4; ++mi)
#pragma unroll
            for (int ks = 0; ks < 2; ++ks)
                av[mi0 + mi][ks] = *(const f16x8*)(p + rowA + (mi0 + mi) * 1024 + koff[ks]);
    };
    auto LD_BV = [&](const f16* p, int nj0) {
#pragma unroll
        for (int nj = 0; nj < 2; ++nj)
#pragma unroll
            for (int ks = 0; ks < 2; ++ks)
                bv[nj0 + nj][ks] = *(const f16x8*)(p + rowB + (nj0 + nj) * 1024 + koff[ks]);
    };
    auto MM = [&](int mi0, int nj0) {
        __builtin_amdgcn_s_setprio(1);
#pragma unroll
        for (int mi = 0; mi < 4; ++mi)
#pragma unroll
            for (int nj = 0; nj < 2; ++nj)
#pragma unroll
                for (int ks = 0; ks < 2; ++ks)
                    acc[mi0 + mi][nj0 + nj] = __builtin_amdgcn_mfma_f32_16x16x32_f16(
                        av[mi0 + mi][ks], bv[nj0 + nj][ks], acc[mi0 + mi][nj0 + nj], 0, 0, 0);
        __builtin_amdgcn_s_setprio(0);
    };

    const int NT = K >> 6;
    int issued = 0, markB = 0;

    STG_A(0, 0, 0); STG_A(0, 1, 0); issued += 4;
    STG_B(0, 0, 0); STG_B(0, 1, 0); issued += 4; markB = issued;
    if (NT > 1) { STG_A(1, 0, 1); STG_A(1, 1, 1); issued += 4; }
    waitvm_n(issued - markB);
    SBAR();

    int iA = 0, iB = 0;
    for (int t = 0; t < NT; ++t) {
        const f16* pA = sA + iA * ASZ;
        const f16* pB = sB + iB * ASZ;
        const int bufB2 = iB ^ 1;
        int bufA2 = iA + 2; if (bufA2 >= 3) bufA2 -= 3;

        LD_BV(pB, 0); LD_AV(pA, 0);
        if (t + 1 < NT) { STG_B(t + 1, 0, bufB2); issued += 2; }
        SBAR(); LGKM0();
        MM(0, 0);
        SBAR();

        LD_BV(pB, 2);
        if (t + 1 < NT) { STG_B(t + 1, 1, bufB2); issued += 2; markB = issued; }
        SBAR(); LGKM0();
        MM(0, 2);
        SBAR();

        LD_AV(pA, 4);
        if (t + 2 < NT) { STG_A(t + 2, 0, bufA2); issued += 2; }
        SBAR(); LGKM0();
        MM(4, 2);
        SBAR();

        if (t + 2 < NT) { STG_A(t + 2, 1, bufA2); issued += 2; }
        if (t + 1 < NT) { waitvm_n(issued - markB); SBAR(); }
        MM(4, 0);
        if (t + 1 < NT) SBAR();

        iA = (iA + 1 == 3) ? 0 : iA + 1;
        iB ^= 1;
    }

    // ---- epilogue: exp -> LDS bounce -> 512B-coalesced stores ----
    const int n0 = bxB * 256;
    const int m0 = bxA * 256;
    f16* bb = smem;
#pragma unroll
    for (int mi = 0; mi < 8; ++mi) {
        const int m    = wm + mi * 16 + ((lane >> 4) << 2);
        const int c16  = m >> 3;
        const int half = m & 4;
#pragma unroll
        for (int nj = 0; nj < 4; ++nj) {
            const int nl = wn + nj * 16 + (lane & 15);
            f16x4 vv;
#pragma unroll
            for (int r = 0; r < 4; ++r)
                vv[r] = (f16)__expf(acc[mi][nj][r] * scale);
            *(f16x4*)(bb + nl * 256 + ((c16 ^ (nl & 7)) << 3) + half) = vv;
        }
    }
    LGKM0();
    SBAR();
#pragma unroll
    for (int it = 0; it < 16; ++it) {
        const int row = it * 16 + (tid >> 5);
        const int ch  = tid & 31;
        f16x8 v = *(const f16x8*)(bb + row * 256 + ((ch ^ (row & 7)) << 3));
        *(f16x8*)(o0 + ((size_t)z * NVAR + n0 + row) * NVAR + m0 + ch * 8) = v;
    }
}

// ---------------------------------------------------------------------------
// 2-phase counted-vmcnt 128(A) x 256(B) GEMM (r12/r15/r17-proven loop),
// templated epilogue.  8 waves (2Ax4B), wave 64x64 (acc[4][4]).
// LDS: A 3-buf(16K) + B 2-buf(32K) = 112 KiB -> 1 blk/CU.
// MODE 0: out  A=S'(16 n-tiles)  B=vwT(2 l-tiles), K=2048; rowsum via
//         ones-MFMA; out[l][n] = acc/rs + bproj[l], float4 along n.
// MODE 1: qkv  A=WqT-stack(12 j-tiles) B=xT(8 n-tiles), K=512; +bias;
//         seg=bxA>>2: 0->q f16x4, 1->k f16x4 (along j), 2->vwT scalar.
// ---------------------------------------------------------------------------
#define AO (128 * 64)
#define BO (256 * 64)
template<int MODE>
__global__ __launch_bounds__(512, 2)
void gemm2p(const f16* __restrict__ A, const f16* __restrict__ B,
            long bsA, long bsB, int lda, int ldb, int K, int nbx,
            const float* __restrict__ bias, float* __restrict__ of,
            f16* __restrict__ o0, f16* __restrict__ o1, f16* __restrict__ o2) {
    __shared__ f16 smem[3 * AO + 2 * BO];
    f16* sA = smem;
    f16* sB = smem + 3 * AO;

    const int tid  = threadIdx.x;
    const int lane = tid & 63;
    const int w    = __builtin_amdgcn_readfirstlane(tid >> 6);
    const int wm   = (w >> 2) * 64;        // over BM=128 (A-dim)
    const int wn   = (w & 3) * 64;         // over BN=256 (B-dim)
    const int z    = blockIdx.x;
    const int bid  = blockIdx.y;
    const int bxA  = bid % nbx;
    const int bxB  = bid / nbx;

    const f16* Ab = A + (size_t)z * bsA + (size_t)bxA * 128 * lda;
    const f16* Bb = B + (size_t)z * bsB + (size_t)bxB * 256 * ldb;

    int offA[2], offB[4];
#pragma unroll
    for (int i = 0; i < 2; ++i) {
        int slot = i * 512 + tid;
        int row  = slot >> 3;
        int s    = (slot & 7) ^ (row & 7);
        offA[i] = row * lda + s * 8;
    }
#pragma unroll
    for (int i = 0; i < 4; ++i) {
        int slot = i * 512 + tid;
        int row  = slot >> 3;
        int s    = (slot & 7) ^ (row & 7);
        offB[i] = row * ldb + s * 8;
    }

    auto STG_A = [&](int kt, int buf) {    // 2 gloads
        f16* d = sA + buf * AO;
#pragma unroll
        for (int i = 0; i < 2; ++i)
            GLOAD(Ab + offA[i] + kt * 64, d + (i * 512 + tid) * 8);
    };
    auto STG_B = [&](int kt, int buf) {    // 4 gloads
        f16* d = sB + buf * BO;
#pragma unroll
        for (int i = 0; i < 4; ++i)
            GLOAD(Bb + offB[i] + kt * 64, d + (i * 512 + tid) * 8);
    };

    int koff[2];
#pragma unroll
    for (int ks = 0; ks < 2; ++ks)
        koff[ks] = ((ks * 4 + (lane >> 4)) ^ (lane & 7)) * 8;
    const int rowA = (wm + (lane & 15)) * 64;
    const int rowB = (wn + (lane & 15)) * 64;

    f16x8 ones;
#pragma unroll
    for (int e = 0; e < 8; ++e) ones[e] = (f16)1.0f;

    f16x8 av[4][2], bv[4][2];
    f32x4 acc[4][4] = {};
    f32x4 accrs[4] = {};

    auto LD_AV = [&](const f16* p, int mi0) {
#pragma unroll
        for (int mi = 0; mi < 2; ++mi)
#pragma unroll
            for (int ks = 0; ks < 2; ++ks)
                av[mi0 + mi][ks] = *(const f16x8*)(p + rowA + (mi0 + mi) * 1024 + koff[ks]);
    };
    auto LD_BV = [&](const f16* p) {
#pragma unroll
        for (int nj = 0; nj < 4; ++nj)
#pragma unroll
            for (int ks = 0; ks < 2; ++ks)
                bv[nj][ks] = *(const f16x8*)(p + rowB + nj * 1024 + koff[ks]);
    };
    auto MM = [&](int mi0) {
        __builtin_amdgcn_s_setprio(1);
#pragma unroll
        for (int mi = 0; mi < 2; ++mi)
#pragma unroll
            for (int ks = 0; ks < 2; ++ks) {
                if constexpr (MODE == 0)
                    accrs[mi0 + mi] = __builtin_amdgcn_mfma_f32_16x16x32_f16(
                        av[mi0 + mi][ks], ones, accrs[mi0 + mi], 0, 0, 0);
#pragma unroll
                for (int nj = 0; nj < 4; ++nj)
                    acc[mi0 + mi][nj] = __builtin_amdgcn_mfma_f32_16x16x32_f16(
                        av[mi0 + mi][ks], bv[nj][ks], acc[mi0 + mi][nj], 0, 0, 0);
            }
        __builtin_amdgcn_s_setprio(0);
    };

    const int NT = K >> 6;
    int issued = 0, markB = 0;

    STG_A(0, 0); issued += 2;
    STG_B(0, 0); issued += 4; markB = issued;
    if (NT > 1) { STG_A(1, 1); issued += 2; }
    waitvm_n(issued - markB);
    SBAR();

    int iA = 0, iB = 0;
    for (int t = 0; t < NT; ++t) {
        const f16* pA = sA + iA * AO;
        const f16* pB = sB + iB * BO;
        int bufA2 = iA + 2; if (bufA2 >= 3) bufA2 -= 3;

        // phase 1: all bv + avL; stage B(t+1)
        LD_BV(pB); LD_AV(pA, 0);
        if (t + 1 < NT) { STG_B(t + 1, iB ^ 1); issued += 4; markB = issued; }
        SBAR(); LGKM0();
        MM(0);
        SBAR();

        // phase 2: avH; stage A(t+2); counted wait
        LD_AV(pA, 2);
        if (t + 2 < NT) { STG_A(t + 2, bufA2); issued += 2; }
        SBAR(); LGKM0();
        MM(2);
        if (t + 1 < NT) { waitvm_n(issued - markB); SBAR(); }

        iA = (iA + 1 == 3) ? 0 : iA + 1;
        iB ^= 1;
    }

    const int rb0 = bxA * 128 + wm + (lane >> 4) * 4;   // A-dim (r contiguous)
    const int cb0 = bxB * 256 + wn + (lane & 15);       // B-dim

    if (MODE == 0) {
        // out[l][n] = acc/rs + bias[l], float4 along n (rb0=n, cb0=l)
#pragma unroll
        for (int mi = 0; mi < 4; ++mi) {
            f32x4 inv;
#pragma unroll
            for (int r = 0; r < 4; ++r) inv[r] = 1.0f / accrs[mi][r];
#pragma unroll
            for (int nj = 0; nj < 4; ++nj) {
                const int l = cb0 + nj * 16;
                const float bb = bias[l];
                f32x4 vv;
#pragma unroll
                for (int r = 0; r < 4; ++r) vv[r] = acc[mi][nj][r] * inv[r] + bb;
                *(f32x4*)(of + ((size_t)z * DM + l) * NVAR + rb0 + mi * 16) = vv;
            }
        }
    } else {
        // qkv: rb0 = j (r contiguous), cb0 = n; seg block-uniform
        const int seg = bxA >> 2;          // 0=q 1=k 2=vw
#pragma unroll
        for (int mi = 0; mi < 4; ++mi) {
            const int j = rb0 + mi * 16;
            const f32x4 b4 = *(const f32x4*)(bias + j);
#pragma unroll
            for (int nj = 0; nj < 4; ++nj) {
                const int n = cb0 + nj * 16;
                if (seg == 2) {
#pragma unroll
                    for (int r = 0; r < 4; ++r)
                        o2[((size_t)z * DM + (j - 1024 + r)) * NVAR + n] =
                            (f16)(acc[mi][nj][r] + b4[r]);
                } else {
                    f16* dst = seg ? o1 : o0;
                    const int jj = seg ? j - 512 : j;
                    f16x4 vv;
#pragma unroll
                    for (int r = 0; r < 4; ++r) vv[r] = (f16)(acc[mi][nj][r] + b4[r]);
                    *(f16x4*)(dst + ((size_t)z * NVAR + n) * DM + jj) = vv;
                }
            }
        }
    }
}

// ---------------------------------------------------------------------------
// r4-proven 128x128 / 4-wave / 256-thr GEMM (weight prep only).
// MODE 4: WvpT A=Wq2(d) B=WpT(l) -> WvpT[l][d] f16x4 along d
// ---------------------------------------------------------------------------
__global__ __launch_bounds__(256)
void gemm_w(const f16* __restrict__ A, const f16* __restrict__ B,
            int lda, int ldb, int K, int nbx, f16* __restrict__ o0) {
    __shared__ f16 sA[128 * 64];
    __shared__ f16 sB[128 * 64];
    const int tid  = threadIdx.x;
    const int lane = tid & 63;
    const int w    = __builtin_amdgcn_readfirstlane(tid >> 6);
    const int wm   = (w >> 1) * 64;
    const int wn   = (w & 1) * 64;
    const int bid  = blockIdx.y;
    const int bxA  = bid % nbx;
    const int bxB  = bid / nbx;

    const f16* Ab = A + (size_t)bxA * 128 * lda;
    const f16* Bb = B + (size_t)bxB * 128 * ldb;

    int srcA[4], srcB[4];
#pragma unroll
    for (int i = 0; i < 4; ++i) {
        int slot = i * 256 + tid;
        int row  = slot >> 3;
        int s    = (slot & 7) ^ (row & 7);
        srcA[i] = row * lda + s * 8;
        srcB[i] = row * ldb + s * 8;
    }

    f32x4 acc[4][4] = {};

    for (int k0 = 0; k0 < K; k0 += 64) {
        __syncthreads();
#pragma unroll
        for (int i = 0; i < 4; ++i) {
            GLOAD(Ab + srcA[i] + k0, sA + i * 2048 + w * 512);
            GLOAD(Bb + srcB[i] + k0, sB + i * 2048 + w * 512);
        }
        __syncthreads();
#pragma unroll
        for (int kh = 0; kh < 2; ++kh) {
            f16x8 av[4], bv[4];
#pragma unroll
            for (int mi = 0; mi < 4; ++mi) {
                int r = wm + mi * 16 + (lane & 15);
                int s = (kh * 4 + (lane >> 4)) ^ (r & 7);
                av[mi] = *(const f16x8*)(sA + r * 64 + s * 8);
            }
#pragma unroll
            for (int nj = 0; nj < 4; ++nj) {
                int r = wn + nj * 16 + (lane & 15);
                int s = (kh * 4 + (lane >> 4)) ^ (r & 7);
                bv[nj] = *(const f16x8*)(sB + r * 64 + s * 8);
            }
#pragma unroll
            for (int mi = 0; mi < 4; ++mi)
#pragma unroll
                for (int nj = 0; nj < 4; ++nj)
                    acc[mi][nj] = __builtin_amdgcn_mfma_f32_16x16x32_f16(
                        av[mi], bv[nj], acc[mi][nj], 0, 0, 0);
        }
    }

    const int rb0 = bxA * 128 + wm + (lane >> 4) * 4;
    const int cb0 = bxB * 128 + wn + (lane & 15);
#pragma unroll
    for (int mi = 0; mi < 4; ++mi)
#pragma unroll
        for (int nj = 0; nj < 4; ++nj) {
            f16x4 vv;
#pragma unroll
            for (int r = 0; r < 4; ++r) vv[r] = (f16)acc[mi][nj][r];
            *(f16x4*)(o0 + ((size_t)(cb0 + nj * 16)) * DM + rb0 + mi * 16) = vv;
        }
}

// ---------------------------------------------------------------------------
extern "C" void kernel_launch(void* const* d_in, const int* in_sizes, int n_in,
                              void* d_out, int out_size, void* d_ws, size_t ws_size,
                              hipStream_t stream) {
    const float* x     = (const float*)d_in[0];
    const float* Wqkv  = (const float*)d_in[1];
    const float* bqkv  = (const float*)d_in[2];
    const float* Wproj = (const float*)d_in[3];
    const float* bproj = (const float*)d_in[4];
    float* out = (float*)d_out;

    const size_t PB = (size_t)NVAR * DM;
    f16* xT   = (f16*)d_ws;                       // [b][n][l]
    f16* q    = xT + 8 * PB;                      // [b][n][d]
    f16* kk   = q  + 8 * PB;                      // [b][m][d]
    f16* vwT  = kk + 8 * PB;                      // [b][l][m]  (V@Wproj)^T
    f16* S    = vwT + 8 * PB;                     // [b][n][m]  (exp values)
    f16* scr  = S  + (size_t)8 * NVAR * NVAR;     // scratch
    f16* WqT  = scr + 8 * PB;                     // [j][l], rows 1024+ = WvpT
    f16* WpT  = WqT + (size_t)J3 * DM;            // [l][d]
    f16* Wq2  = scr;                              // [d][j] f16 cast of W_v
    float* bias_c = (float*)(scr + 512 * 512);    // [1536]

    k_tr<<<dim3(NVAR / 64, DM / 64, 8), 256, 0, stream>>>(
        x, xT, DM, NVAR, (long)DM * NVAR, (long)NVAR * DM);
    k_tr<<<dim3(16, DM / 64, 1), 256, 0, stream>>>(Wqkv, WqT, DM, J3, 0, 0);
    k_tr<<<dim3(DM / 64, DM / 64, 1), 256, 0, stream>>>(Wproj, WpT, DM, DM, 0, 0);
    k_cast<<<dim3(256), 256, 0, stream>>>(Wqkv, Wq2);
    k_bvp<<<dim3(8), 256, 0, stream>>>(bqkv, Wproj, bias_c);

    // WvpT = (Wv@Wproj)^T: A=Wq2 (4 d-tiles), B=WpT (4 l-tiles), K=512
    gemm_w<<<dim3(1, 16), 256, 0, stream>>>(
        Wq2, WpT, 512, DM, DM, 4, WqT + (size_t)1024 * DM);

    // qkv: 2-phase 128x256, A=WqT-stack (12 j-tiles), B=xT (8 n-tiles),
    // K=512 -> 96 blk/batch = 768 blocks (3 exact rounds @ 1 blk/CU)
    gemm2p<1><<<dim3(8, 12 * 8), 512, 0, stream>>>(
        WqT, xT, 0, (long)NVAR * DM, DM, DM, DM, 12,
        bias_c, nullptr, q, kk, vwT);

    // S' = exp(q@k^T*scale): 8-phase 256^2 + bounced stores -> 512 blocks
    gemm_sp<<<dim3(8, 8 * 8), 512, 0, stream>>>(
        kk, q, (long)NVAR * DM, (long)NVAR * DM, DM, DM, DM,
        0.044194173824159216f, S);

    // out = (S'@vwT)/rowsum + bproj: A=S' (16 n-tiles), B=vwT (2 l-tiles),
    // K=2048 -> 256 blocks
    gemm2p<0><<<dim3(8, 32), 512, 0, stream>>>(
        S, vwT, (long)NVAR * NVAR, (long)DM * NVAR, NVAR, NVAR, NVAR, 16,
        bproj, out, nullptr, nullptr, nullptr);
}

// Round 19
// 173.510 us; speedup vs baseline: 1.0201x; 1.0201x over previous
//
#include <hip/hip_runtime.h>

#define NVAR 2048
#define DM   512
#define J3   1536

typedef _Float16 f16;
typedef _Float16 f16x8 __attribute__((ext_vector_type(8)));
typedef _Float16 f16x4 __attribute__((ext_vector_type(4)));
typedef float    f32x4 __attribute__((ext_vector_type(4)));

#define SBAR() do { asm volatile("s_barrier" ::: "memory"); \
                    __builtin_amdgcn_sched_barrier(0); } while(0)
#define LGKM0() do { asm volatile("s_waitcnt lgkmcnt(0)" ::: "memory"); \
                     __builtin_amdgcn_sched_barrier(0); } while(0)
#define GLOAD(gp, lp) __builtin_amdgcn_global_load_lds( \
    (const __attribute__((address_space(1))) void*)(gp), \
    (__attribute__((address_space(3))) void*)(lp), 16, 0, 0)

__device__ __forceinline__ void waitvm_n(int n) {
    switch (n) {
    case 0: asm volatile("s_waitcnt vmcnt(0)" ::: "memory"); break;
    case 1: asm volatile("s_waitcnt vmcnt(1)" ::: "memory"); break;
    case 2: asm volatile("s_waitcnt vmcnt(2)" ::: "memory"); break;
    case 3: asm volatile("s_waitcnt vmcnt(3)" ::: "memory"); break;
    case 4: asm volatile("s_waitcnt vmcnt(4)" ::: "memory"); break;
    case 5: asm volatile("s_waitcnt vmcnt(5)" ::: "memory"); break;
    case 6: asm volatile("s_waitcnt vmcnt(6)" ::: "memory"); break;
    case 7: asm volatile("s_waitcnt vmcnt(7)" ::: "memory"); break;
    case 8: asm volatile("s_waitcnt vmcnt(8)" ::: "memory"); break;
    default: break;
    }
    __builtin_amdgcn_sched_barrier(0);
}

// ---------------------------------------------------------------------------
// Transpose fp32 [R][C] -> f16 [C][R] (per grid.z batch), vectorized
// ---------------------------------------------------------------------------
__global__ __launch_bounds__(256)
void k_tr(const float* __restrict__ src, f16* __restrict__ dst,
          int R, int C, long bsSrc, long bsDst) {
    __shared__ float t[64][65];
    const float* s = src + (size_t)blockIdx.z * bsSrc;
    f16* d = dst + (size_t)blockIdx.z * bsDst;
    const int c0 = blockIdx.x * 64, r0 = blockIdx.y * 64;
    const int lx = threadIdx.x & 15, ly = threadIdx.x >> 4;
#pragma unroll
    for (int p = 0; p < 4; ++p) {
        int r = p * 16 + ly;
        f32x4 v = *(const f32x4*)(s + (size_t)(r0 + r) * C + c0 + lx * 4);
#pragma unroll
        for (int i = 0; i < 4; ++i) t[r][lx * 4 + i] = v[i];
    }
    __syncthreads();
#pragma unroll
    for (int p = 0; p < 4; ++p) {
        int c = p * 16 + ly;
        f16x4 h;
#pragma unroll
        for (int i = 0; i < 4; ++i) h[i] = (f16)t[lx * 4 + i][c];
        *(f16x4*)(d + (size_t)(c0 + c) * R + r0 + lx * 4) = h;
    }
}

// ---------------------------------------------------------------------------
// Cast Wqkv[:,1024:1536] fp32 -> f16 Wq2[d][j]
// ---------------------------------------------------------------------------
__global__ __launch_bounds__(256)
void k_cast(const float* __restrict__ W, f16* __restrict__ out) {
    int idx = blockIdx.x * 256 + threadIdx.x;
    int gi = idx * 4;
    int d = gi >> 9, j = gi & 511;
    f32x4 v = *(const f32x4*)(W + (size_t)d * J3 + 1024 + j);
    f16x4 h;
#pragma unroll
    for (int i = 0; i < 4; ++i) h[i] = (f16)v[i];
    *(f16x4*)(out + (size_t)d * 512 + j) = h;
}

// ---------------------------------------------------------------------------
// bias_c: [0:1024] = bqkv[0:1024]; [1024+l] = sum_j bqkv[1024+j]*Wp[j][l].
// ---------------------------------------------------------------------------
__global__ __launch_bounds__(256)
void k_bvp(const float* __restrict__ bqkv, const float* __restrict__ Wp,
           float* __restrict__ bias_c) {
    const int b = blockIdx.x;
    const int lt = threadIdx.x & 63, js = threadIdx.x >> 6;
    const int l = b * 64 + lt;
    float s = 0.f;
    for (int j = js * 128; j < js * 128 + 128; ++j)
        s += bqkv[1024 + j] * Wp[(size_t)j * DM + l];
    __shared__ float red[4][64];
    red[js][lt] = s;
    __syncthreads();
    if (js == 0)
        bias_c[1024 + l] = (red[0][lt] + red[1][lt]) + (red[2][lt] + red[3][lt]);
    if (threadIdx.x < 128) {
        int i = b * 128 + threadIdx.x;
        bias_c[i] = bqkv[i];
    }
}

// ---------------------------------------------------------------------------
// S' 8-phase counted-vmcnt GEMM (r10/r12/r17-proven): 256x256, BK=64,
// 512 thr, 8 waves (2Mx4N), wave 128x64.  A x3 + B x2 LDS = 160 KiB.
// Epilogue: exp(acc*scale) -> LDS bounce -> 512B-coalesced stores.
// ---------------------------------------------------------------------------
#define ASZ (256 * 64)
__global__ __launch_bounds__(512, 2)
void gemm_sp(const f16* __restrict__ A, const f16* __restrict__ B,
             long bsA, long bsB, int lda, int ldb, int K,
             float scale, f16* __restrict__ o0) {
    __shared__ f16 smem[5 * ASZ];
    f16* sA = smem;
    f16* sB = smem + 3 * ASZ;

    const int tid  = threadIdx.x;
    const int lane = tid & 63;
    const int w    = __builtin_amdgcn_readfirstlane(tid >> 6);
    const int wm   = (w >> 2) * 128;       // A-dim (m)
    const int wn   = (w & 3) * 64;         // B-dim (n)
    const int z    = blockIdx.x;
    const int bid  = blockIdx.y;
    const int bxA  = bid & 7;
    const int bxB  = bid >> 3;

    const f16* Ab = A + (size_t)z * bsA + (size_t)bxA * 256 * lda;
    const f16* Bb = B + (size_t)z * bsB + (size_t)bxB * 256 * ldb;

    int offA[2][2], offB[2][2];
#pragma unroll
    for (int h = 0; h < 2; ++h)
#pragma unroll
        for (int i = 0; i < 2; ++i) {
            int slot = i * 512 + tid;
            int row  = h * 128 + (slot >> 3);
            int s    = (slot & 7) ^ (row & 7);
            offA[h][i] = row * lda + s * 8;
            offB[h][i] = row * ldb + s * 8;
        }

    auto STG_A = [&](int kt, int h, int buf) {
        f16* d = sA + buf * ASZ + h * 8192;
#pragma unroll
        for (int i = 0; i < 2; ++i)
            GLOAD(Ab + offA[h][i] + kt * 64, d + (i * 512 + tid) * 8);
    };
    auto STG_B = [&](int kt, int h, int buf) {
        f16* d = sB + buf * ASZ + h * 8192;
#pragma unroll
        for (int i = 0; i < 2; ++i)
            GLOAD(Bb + offB[h][i] + kt * 64, d + (i * 512 + tid) * 8);
    };

    int koff[2];
#pragma unroll
    for (int ks = 0; ks < 2; ++ks)
        koff[ks] = ((ks * 4 + (lane >> 4)) ^ (lane & 7)) * 8;
    const int rowA = (wm + (lane & 15)) * 64;
    const int rowB = (wn + (lane & 15)) * 64;

    f16x8 av[8][2], bv[4][2];
    f32x4 acc[8][4] = {};

    auto LD_AV = [&](const f16* p, int mi0) {
#pragma unroll
        for (int mi = 0; mi < 4; ++mi)
#pragma unroll
            for (int ks = 0; ks < 2; ++ks)
                av[mi0 + mi][ks] = *(const f16x8*)(p + rowA + (mi0 + mi) * 1024 + koff[ks]);
    };
    auto LD_BV = [&](const f16* p, int nj0) {
#pragma unroll
        for (int nj = 0; nj < 2; ++nj)
#pragma unroll
            for (int ks = 0; ks < 2; ++ks)
                bv[nj0 + nj][ks] = *(const f16x8*)(p + rowB + (nj0 + nj) * 1024 + koff[ks]);
    };
    auto MM = [&](int mi0, int nj0) {
        __builtin_amdgcn_s_setprio(1);
#pragma unroll
        for (int mi = 0; mi < 4; ++mi)
#pragma unroll
            for (int nj = 0; nj < 2; ++nj)
#pragma unroll
                for (int ks = 0; ks < 2; ++ks)
                    acc[mi0 + mi][nj0 + nj] = __builtin_amdgcn_mfma_f32_16x16x32_f16(
                        av[mi0 + mi][ks], bv[nj0 + nj][ks], acc[mi0 + mi][nj0 + nj], 0, 0, 0);
        __builtin_amdgcn_s_setprio(0);
    };

    const int NT = K >> 6;
    int issued = 0, markB = 0;

    STG_A(0, 0, 0); STG_A(0, 1, 0); issued += 4;
    STG_B(0, 0, 0); STG_B(0, 1, 0); issued += 4; markB = issued;
    if (NT > 1) { STG_A(1, 0, 1); STG_A(1, 1, 1); issued += 4; }
    waitvm_n(issued - markB);
    SBAR();

    int iA = 0, iB = 0;
    for (int t = 0; t < NT; ++t) {
        const f16* pA = sA + iA * ASZ;
        const f16* pB = sB + iB * ASZ;
        const int bufB2 = iB ^ 1;
        int bufA2 = iA + 2; if (bufA2 >= 3) bufA2 -= 3;

        LD_BV(pB, 0); LD_AV(pA, 0);
        if (t + 1 < NT) { STG_B(t + 1, 0, bufB2); issued += 2; }
        SBAR(); LGKM0();
        MM(0, 0);
        SBAR();

        LD_BV(pB, 2);
        if (t + 1 < NT) { STG_B(t + 1, 1, bufB2); issued += 2; markB = issued; }
        SBAR(); LGKM0();
        MM(0, 2);
        SBAR();

        LD_AV(pA, 4);
        if (t + 2 < NT) { STG_A(t + 2, 0, bufA2); issued += 2; }
        SBAR(); LGKM0();
        MM(4, 2);
        SBAR();

        if (t + 2 < NT) { STG_A(t + 2, 1, bufA2); issued += 2; }
        if (t + 1 < NT) { waitvm_n(issued - markB); SBAR(); }
        MM(4, 0);
        if (t + 1 < NT) SBAR();

        iA = (iA + 1 == 3) ? 0 : iA + 1;
        iB ^= 1;
    }

    // ---- epilogue: exp -> LDS bounce -> 512B-coalesced stores ----
    const int n0 = bxB * 256;
    const int m0 = bxA * 256;
    f16* bb = smem;
#pragma unroll
    for (int mi = 0; mi < 8; ++mi) {
        const int m    = wm + mi * 16 + ((lane >> 4) << 2);
        const int c16  = m >> 3;
        const int half = m & 4;
#pragma unroll
        for (int nj = 0; nj < 4; ++nj) {
            const int nl = wn + nj * 16 + (lane & 15);
            f16x4 vv;
#pragma unroll
            for (int r = 0; r < 4; ++r)
                vv[r] = (f16)__expf(acc[mi][nj][r] * scale);
            *(f16x4*)(bb + nl * 256 + ((c16 ^ (nl & 7)) << 3) + half) = vv;
        }
    }
    LGKM0();
    SBAR();
#pragma unroll
    for (int it = 0; it < 16; ++it) {
        const int row = it * 16 + (tid >> 5);
        const int ch  = tid & 31;
        f16x8 v = *(const f16x8*)(bb + row * 256 + ((ch ^ (row & 7)) << 3));
        *(f16x8*)(o0 + ((size_t)z * NVAR + n0 + row) * NVAR + m0 + ch * 8) = v;
    }
}

// ---------------------------------------------------------------------------
// out-GEMM (fused PV+proj), 128n x 256l: A=S' (16 n-tiles of 128),
// B=vwT (2 l-tiles of 256), K=2048 -> 32 blk/batch = 256 blocks.
// Ledger: A 3-buf(16K), B 2-buf(32K) = 112 KiB; rowsum via mfma(av, ones).
// out[l][n] = acc/rs[n] + bproj[l], fp32 float4 along n.
// ---------------------------------------------------------------------------
#define AO (128 * 64)
#define BO (256 * 64)
__global__ __launch_bounds__(512, 2)
void gemm_out(const f16* __restrict__ A, const f16* __restrict__ B,
              long bsA, long bsB, int lda, int ldb, int K,
              const float* __restrict__ bias, float* __restrict__ of) {
    __shared__ f16 smem[3 * AO + 2 * BO];
    f16* sA = smem;
    f16* sB = smem + 3 * AO;

    const int tid  = threadIdx.x;
    const int lane = tid & 63;
    const int w    = __builtin_amdgcn_readfirstlane(tid >> 6);
    const int wm   = (w >> 2) * 64;        // over BM=128 (n)
    const int wn   = (w & 3) * 64;         // over BN=256 (l)
    const int z    = blockIdx.x;
    const int bid  = blockIdx.y;
    const int bxA  = bid & 15;             // 16 n-tiles
    const int bxB  = bid >> 4;             // 2 l-tiles

    const f16* Ab = A + (size_t)z * bsA + (size_t)bxA * 128 * lda;
    const f16* Bb = B + (size_t)z * bsB + (size_t)bxB * 256 * ldb;

    int offA[2], offB[4];
#pragma unroll
    for (int i = 0; i < 2; ++i) {
        int slot = i * 512 + tid;
        int row  = slot >> 3;
        int s    = (slot & 7) ^ (row & 7);
        offA[i] = row * lda + s * 8;
    }
#pragma unroll
    for (int i = 0; i < 4; ++i) {
        int slot = i * 512 + tid;
        int row  = slot >> 3;
        int s    = (slot & 7) ^ (row & 7);
        offB[i] = row * ldb + s * 8;
    }

    auto STG_A = [&](int kt, int buf) {    // 2 gloads
        f16* d = sA + buf * AO;
#pragma unroll
        for (int i = 0; i < 2; ++i)
            GLOAD(Ab + offA[i] + kt * 64, d + (i * 512 + tid) * 8);
    };
    auto STG_B = [&](int kt, int buf) {    // 4 gloads
        f16* d = sB + buf * BO;
#pragma unroll
        for (int i = 0; i < 4; ++i)
            GLOAD(Bb + offB[i] + kt * 64, d + (i * 512 + tid) * 8);
    };

    int koff[2];
#pragma unroll
    for (int ks = 0; ks < 2; ++ks)
        koff[ks] = ((ks * 4 + (lane >> 4)) ^ (lane & 7)) * 8;
    const int rowA = (wm + (lane & 15)) * 64;
    const int rowB = (wn + (lane & 15)) * 64;

    f16x8 ones;
#pragma unroll
    for (int e = 0; e < 8; ++e) ones[e] = (f16)1.0f;

    f16x8 av[4][2], bv[4][2];
    f32x4 acc[4][4] = {};
    f32x4 accrs[4] = {};

    auto LD_AV = [&](const f16* p, int mi0) {
#pragma unroll
        for (int mi = 0; mi < 2; ++mi)
#pragma unroll
            for (int ks = 0; ks < 2; ++ks)
                av[mi0 + mi][ks] = *(const f16x8*)(p + rowA + (mi0 + mi) * 1024 + koff[ks]);
    };
    auto LD_BV = [&](const f16* p) {
#pragma unroll
        for (int nj = 0; nj < 4; ++nj)
#pragma unroll
            for (int ks = 0; ks < 2; ++ks)
                bv[nj][ks] = *(const f16x8*)(p + rowB + nj * 1024 + koff[ks]);
    };
    auto MM = [&](int mi0) {
        __builtin_amdgcn_s_setprio(1);
#pragma unroll
        for (int mi = 0; mi < 2; ++mi)
#pragma unroll
            for (int ks = 0; ks < 2; ++ks) {
                accrs[mi0 + mi] = __builtin_amdgcn_mfma_f32_16x16x32_f16(
                    av[mi0 + mi][ks], ones, accrs[mi0 + mi], 0, 0, 0);
#pragma unroll
                for (int nj = 0; nj < 4; ++nj)
                    acc[mi0 + mi][nj] = __builtin_amdgcn_mfma_f32_16x16x32_f16(
                        av[mi0 + mi][ks], bv[nj][ks], acc[mi0 + mi][nj], 0, 0, 0);
            }
        __builtin_amdgcn_s_setprio(0);
    };

    const int NT = K >> 6;
    int issued = 0, markB = 0;

    STG_A(0, 0); issued += 2;
    STG_B(0, 0); issued += 4; markB = issued;
    if (NT > 1) { STG_A(1, 1); issued += 2; }
    waitvm_n(issued - markB);
    SBAR();

    int iA = 0, iB = 0;
    for (int t = 0; t < NT; ++t) {
        const f16* pA = sA + iA * AO;
        const f16* pB = sB + iB * BO;
        int bufA2 = iA + 2; if (bufA2 >= 3) bufA2 -= 3;

        // phase 1: all bv + avL; stage B(t+1)
        LD_BV(pB); LD_AV(pA, 0);
        if (t + 1 < NT) { STG_B(t + 1, iB ^ 1); issued += 4; markB = issued; }
        SBAR(); LGKM0();
        MM(0);
        SBAR();

        // phase 2: avH; stage A(t+2); counted wait
        LD_AV(pA, 2);
        if (t + 2 < NT) { STG_A(t + 2, bufA2); issued += 2; }
        SBAR(); LGKM0();
        MM(2);
        if (t + 1 < NT) { waitvm_n(issued - markB); SBAR(); }

        iA = (iA + 1 == 3) ? 0 : iA + 1;
        iB ^= 1;
    }

    // epilogue: out[l][n] = acc/rs + bias[l], float4 along n
    const int rb0 = bxA * 128 + wm + (lane >> 4) * 4;   // n
    const int cb0 = bxB * 256 + wn + (lane & 15);       // l
#pragma unroll
    for (int mi = 0; mi < 4; ++mi) {
        f32x4 inv;
#pragma unroll
        for (int r = 0; r < 4; ++r) inv[r] = 1.0f / accrs[mi][r];
#pragma unroll
        for (int nj = 0; nj < 4; ++nj) {
            const int l = cb0 + nj * 16;
            const float bb = bias[l];
            f32x4 vv;
#pragma unroll
            for (int r = 0; r < 4; ++r) vv[r] = acc[mi][nj][r] * inv[r] + bb;
            *(f32x4*)(of + ((size_t)z * DM + l) * NVAR + rb0 + mi * 16) = vv;
        }
    }
}

// ---------------------------------------------------------------------------
// r4-proven 128x128 / 4-wave / 256-thr GEMM (r12-proven epilogues).
// MODE 0: qkv  A=WqT/WvpT(j) B=xT(n) -> q/k f16x4 (+bias); seg2 -> vwT scalar
// MODE 4: WvpT A=Wq2(d) B=WpT(l) -> WvpT[l][d] f16x4 along d
// ---------------------------------------------------------------------------
template<int MODE>
__global__ __launch_bounds__(256)
void gemm_f16(const f16* __restrict__ A, const f16* __restrict__ B,
              long bsA, long bsB, int lda, int ldb, int K, int nbx,
              const float* __restrict__ bias,
              f16* __restrict__ o0, f16* __restrict__ o1, f16* __restrict__ o2) {
    __shared__ f16 sA[128 * 64];
    __shared__ f16 sB[128 * 64];
    const int tid  = threadIdx.x;
    const int lane = tid & 63;
    const int w    = __builtin_amdgcn_readfirstlane(tid >> 6);
    const int wm   = (w >> 1) * 64;
    const int wn   = (w & 1) * 64;
    const int z    = blockIdx.x;
    const int bid  = blockIdx.y;
    const int bxA  = bid % nbx;
    const int bxB  = bid / nbx;

    const f16* Ab = A + (size_t)z * bsA + (size_t)bxA * 128 * lda;
    const f16* Bb = B + (size_t)z * bsB + (size_t)bxB * 128 * ldb;

    int srcA[4], srcB[4];
#pragma unroll
    for (int i = 0; i < 4; ++i) {
        int slot = i * 256 + tid;
        int row  = slot >> 3;
        int s    = (slot & 7) ^ (row & 7);
        srcA[i] = row * lda + s * 8;
        srcB[i] = row * ldb + s * 8;
    }

    f32x4 acc[4][4] = {};

    for (int k0 = 0; k0 < K; k0 += 64) {
        __syncthreads();
#pragma unroll
        for (int i = 0; i < 4; ++i) {
            GLOAD(Ab + srcA[i] + k0, sA + i * 2048 + w * 512);
            GLOAD(Bb + srcB[i] + k0, sB + i * 2048 + w * 512);
        }
        __syncthreads();
#pragma unroll
        for (int kh = 0; kh < 2; ++kh) {
            f16x8 av[4], bv[4];
#pragma unroll
            for (int mi = 0; mi < 4; ++mi) {
                int r = wm + mi * 16 + (lane & 15);
                int s = (kh * 4 + (lane >> 4)) ^ (r & 7);
                av[mi] = *(const f16x8*)(sA + r * 64 + s * 8);
            }
#pragma unroll
            for (int nj = 0; nj < 4; ++nj) {
                int r = wn + nj * 16 + (lane & 15);
                int s = (kh * 4 + (lane >> 4)) ^ (r & 7);
                bv[nj] = *(const f16x8*)(sB + r * 64 + s * 8);
            }
#pragma unroll
            for (int mi = 0; mi < 4; ++mi)
#pragma unroll
                for (int nj = 0; nj < 4; ++nj)
                    acc[mi][nj] = __builtin_amdgcn_mfma_f32_16x16x32_f16(
                        av[mi], bv[nj], acc[mi][nj], 0, 0, 0);
        }
    }

    const int rb0 = bxA * 128 + wm + (lane >> 4) * 4;
    const int cb0 = bxB * 128 + wn + (lane & 15);

    if (MODE == 0) {
        const int seg = (bxA * 128) >> 9;   // 0=q 1=k 2=vw (block-uniform)
#pragma unroll
        for (int mi = 0; mi < 4; ++mi) {
            const int j = rb0 + mi * 16;
            const f32x4 b4 = *(const f32x4*)(bias + j);
#pragma unroll
            for (int nj = 0; nj < 4; ++nj) {
                const int n = cb0 + nj * 16;
                if (seg == 2) {
#pragma unroll
                    for (int r = 0; r < 4; ++r)
                        o2[((size_t)z * DM + (j - 1024 + r)) * NVAR + n] =
                            (f16)(acc[mi][nj][r] + b4[r]);
                } else {
                    f16* dst = seg ? o1 : o0;
                    const int jj = seg ? j - 512 : j;
                    f16x4 vv;
#pragma unroll
                    for (int r = 0; r < 4; ++r) vv[r] = (f16)(acc[mi][nj][r] + b4[r]);
                    *(f16x4*)(dst + ((size_t)z * NVAR + n) * DM + jj) = vv;
                }
            }
        }
    } else {
        // WvpT[l][d]: l = cb0+nj*16, d = rb0+mi*16+r (f16x4 along d)
#pragma unroll
        for (int mi = 0; mi < 4; ++mi)
#pragma unroll
            for (int nj = 0; nj < 4; ++nj) {
                f16x4 vv;
#pragma unroll
                for (int r = 0; r < 4; ++r) vv[r] = (f16)acc[mi][nj][r];
                *(f16x4*)(o0 + ((size_t)(cb0 + nj * 16)) * DM
                               + rb0 + mi * 16) = vv;
            }
    }
}

// ---------------------------------------------------------------------------
extern "C" void kernel_launch(void* const* d_in, const int* in_sizes, int n_in,
                              void* d_out, int out_size, void* d_ws, size_t ws_size,
                              hipStream_t stream) {
    const float* x     = (const float*)d_in[0];
    const float* Wqkv  = (const float*)d_in[1];
    const float* bqkv  = (const float*)d_in[2];
    const float* Wproj = (const float*)d_in[3];
    const float* bproj = (const float*)d_in[4];
    float* out = (float*)d_out;

    const size_t PB = (size_t)NVAR * DM;
    f16* xT   = (f16*)d_ws;                       // [b][n][l]
    f16* q    = xT + 8 * PB;                      // [b][n][d]
    f16* kk   = q  + 8 * PB;                      // [b][m][d]
    f16* vwT  = kk + 8 * PB;                      // [b][l][m]  (V@Wproj)^T
    f16* S    = vwT + 8 * PB;                     // [b][n][m]  (exp values)
    f16* scr  = S  + (size_t)8 * NVAR * NVAR;     // scratch
    f16* WqT  = scr + 8 * PB;                     // [j][l], rows 1024+ = WvpT
    f16* WpT  = WqT + (size_t)J3 * DM;            // [l][d]
    f16* Wq2  = scr;                              // [d][j] f16 cast of W_v
    float* bias_c = (float*)(scr + 512 * 512);    // [1536]

    k_tr<<<dim3(NVAR / 64, DM / 64, 8), 256, 0, stream>>>(
        x, xT, DM, NVAR, (long)DM * NVAR, (long)NVAR * DM);
    k_tr<<<dim3(16, DM / 64, 1), 256, 0, stream>>>(Wqkv, WqT, DM, J3, 0, 0);
    k_tr<<<dim3(DM / 64, DM / 64, 1), 256, 0, stream>>>(Wproj, WpT, DM, DM, 0, 0);
    k_cast<<<dim3(256), 256, 0, stream>>>(Wqkv, Wq2);
    k_bvp<<<dim3(8), 256, 0, stream>>>(bqkv, Wproj, bias_c);

    // WvpT = (Wv@Wproj)^T: A=Wq2 (4 d-tiles), B=WpT (4 l-tiles), K=512
    gemm_f16<4><<<dim3(1, 16), 256, 0, stream>>>(
        Wq2, WpT, 0, 0, 512, DM, DM, 4,
        nullptr, WqT + (size_t)1024 * DM, nullptr, nullptr);

    // qkv: A=WqT[1536][512] (12 j-tiles; rows 1024+ = WvpT), B=xT (16 n-tiles)
    gemm_f16<0><<<dim3(8, 12 * 16), 256, 0, stream>>>(
        WqT, xT, 0, (long)NVAR * DM, DM, DM, DM, 12,
        bias_c, q, kk, vwT);

    // S' = exp(q@k^T*scale): 8-phase 256^2 + bounced stores -> 512 blocks
    gemm_sp<<<dim3(8, 8 * 8), 512, 0, stream>>>(
        kk, q, (long)NVAR * DM, (long)NVAR * DM, DM, DM, DM,
        0.044194173824159216f, S);

    // out = (S'@vwT)/rowsum + bproj: 128n x 256l tiles, 256 blocks, K=2048
    gemm_out<<<dim3(8, 32), 512, 0, stream>>>(
        S, vwT, (long)NVAR * NVAR, (long)DM * NVAR, NVAR, NVAR, NVAR,
        bproj, out);
}